// Round 9
// baseline (151.896 us; speedup 1.0000x reference)
//
#include <hip/hip_runtime.h>
#include <math.h>

#define B_ 2
#define T_ 256
#define DM_ 512
#define H_ 8
#define DH_ 64
#define HID_ 128
#define GH_ 64
#define NMEM_ 32768
#define TOPK_ 32
#define BT_ (B_*T_)      // 512
#define HD_ (H_*DH_)     // 512
#define SELC_ 8192
#define NCHUNK_ (NMEM_/SELC_)  // 4
#define TT_ 16           // t-tile for fused attention (512 threads)
#define EQCAP_ 512
#define NTILE_ 256       // NMEM_/128
#define CCAP_ 2048

// ---------------- fused QKV + gelu-gate projections ----------------
__global__ __launch_bounds__(256) void awm_qkvg_kernel(
    const float* __restrict__ x,
    const float* __restrict__ Wq, const float* __restrict__ Wk, const float* __restrict__ Wv,
    const float* __restrict__ Wg1, const float* __restrict__ bg1,
    const float* __restrict__ Wg2, const float* __restrict__ bg2,
    float* __restrict__ q, float* __restrict__ k, float* __restrict__ v,
    float* __restrict__ gates) {
    int z = blockIdx.z;
    if (z == 3 && blockIdx.x != 0) return;
    const float* W = (z == 0) ? Wq : (z == 1) ? Wk : (z == 2) ? Wv : Wg1;
    float* C = (z == 0) ? q : (z == 1) ? k : v;
    const int N = (z == 3) ? GH_ : HD_;
    __shared__ float As[32][34];
    __shared__ float Bs[32][68];
    int bm = blockIdx.y * 32, bn = blockIdx.x * 64;
    int tid = threadIdx.x;
    int tm = (tid >> 4) * 2, tn = (tid & 15) * 4;
    float acc[2][4] = {};
    for (int k0 = 0; k0 < DM_; k0 += 32) {
        {
            int m = tid >> 3, kk = (tid & 7) * 4;
            float4 a = *(const float4*)&x[(size_t)(bm + m) * DM_ + k0 + kk];
            As[kk+0][m] = a.x; As[kk+1][m] = a.y; As[kk+2][m] = a.z; As[kk+3][m] = a.w;
#pragma unroll
            for (int p = 0; p < 2; ++p) {
                int idx = tid * 4 + p * 1024;
                int kb = idx >> 6, n = idx & 63;
                *(float4*)&Bs[kb][n] = *(const float4*)&W[(size_t)(k0 + kb) * N + bn + n];
            }
        }
        __syncthreads();
#pragma unroll
        for (int kk = 0; kk < 32; ++kk) {
            float2 a2 = *(const float2*)&As[kk][tm];
            float4 b4 = *(const float4*)&Bs[kk][tn];
            acc[0][0] += a2.x * b4.x; acc[0][1] += a2.x * b4.y;
            acc[0][2] += a2.x * b4.z; acc[0][3] += a2.x * b4.w;
            acc[1][0] += a2.y * b4.x; acc[1][1] += a2.y * b4.y;
            acc[1][2] += a2.y * b4.z; acc[1][3] += a2.y * b4.w;
        }
        __syncthreads();
    }
    if (z < 3) {
#pragma unroll
        for (int xr = 0; xr < 2; ++xr) {
            float4 r; r.x = acc[xr][0]; r.y = acc[xr][1]; r.z = acc[xr][2]; r.w = acc[xr][3];
            *(float4*)&C[(size_t)(bm + tm + xr) * HD_ + bn + tn] = r;
        }
    } else {
#pragma unroll
        for (int xr = 0; xr < 2; ++xr)
#pragma unroll
            for (int y = 0; y < 4; ++y) {
                float vv = acc[xr][y] + bg1[tn + y];
                float u = 0.7978845608028654f * (vv + 0.044715f * vv * vv * vv);
                Bs[tm + xr][tn + y] = 0.5f * vv * (1.f + tanhf(u));
            }
        float* wg = &As[0][0];
        for (int i = tid; i < GH_ * H_; i += 256) wg[i] = Wg2[i];
        __syncthreads();
        int r = tid >> 3, hh = tid & 7;
        float acg = bg2[hh];
#pragma unroll
        for (int j = 0; j < GH_; ++j) acg += Bs[r][j] * wg[j * H_ + hh];
        gates[(size_t)(bm + r) * H_ + hh] = 1.f / (1.f + expf(-acg));
    }
}

// ---------------- output projection: y = outg @ Wo ----------------
__global__ __launch_bounds__(256) void awm_out_kernel(
    const float* __restrict__ A, const float* __restrict__ W, float* __restrict__ C) {
    __shared__ float As[32][34];
    __shared__ float Bs[32][68];
    int bm = blockIdx.y * 32, bn = blockIdx.x * 64;
    int tid = threadIdx.x;
    int tm = (tid >> 4) * 2, tn = (tid & 15) * 4;
    float acc[2][4] = {};
    for (int k0 = 0; k0 < HD_; k0 += 32) {
        {
            int m = tid >> 3, kk = (tid & 7) * 4;
            float4 a = *(const float4*)&A[(size_t)(bm + m) * HD_ + k0 + kk];
            As[kk+0][m] = a.x; As[kk+1][m] = a.y; As[kk+2][m] = a.z; As[kk+3][m] = a.w;
#pragma unroll
            for (int p = 0; p < 2; ++p) {
                int idx = tid * 4 + p * 1024;
                int kb = idx >> 6, n = idx & 63;
                *(float4*)&Bs[kb][n] = *(const float4*)&W[(size_t)(k0 + kb) * DM_ + bn + n];
            }
        }
        __syncthreads();
#pragma unroll
        for (int kk = 0; kk < 32; ++kk) {
            float2 a2 = *(const float2*)&As[kk][tm];
            float4 b4 = *(const float4*)&Bs[kk][tn];
            acc[0][0] += a2.x * b4.x; acc[0][1] += a2.x * b4.y;
            acc[0][2] += a2.x * b4.z; acc[0][3] += a2.x * b4.w;
            acc[1][0] += a2.y * b4.x; acc[1][1] += a2.y * b4.y;
            acc[1][2] += a2.y * b4.z; acc[1][3] += a2.y * b4.w;
        }
        __syncthreads();
    }
#pragma unroll
    for (int xr = 0; xr < 2; ++xr) {
        float4 r; r.x = acc[xr][0]; r.y = acc[xr][1]; r.z = acc[xr][2]; r.w = acc[xr][3];
        *(float4*)&C[(size_t)(bm + tm + xr) * DM_ + bn + tn] = r;
    }
}

// ---------------- sel GEMM (+fused q-mean) + per-(row,128-tile) max ----------------
// qm computed in-block from q_flat: thread (m=tid>>2, dq=(tid&3)*16) holds 16 means.
// Exact same per-d summation order (h ascending, then *0.125) as the old qmean kernel.
__global__ __launch_bounds__(256) void awm_selgemm_kernel(
    const float* __restrict__ q_flat, const float* __restrict__ mkeys,
    float* __restrict__ selc, float* __restrict__ tmax, int chunk0, int ld) {
    __shared__ float Qs[32][68];
    __shared__ float Ks[32][132];
    int bn = blockIdx.x * 128;
    int bm = blockIdx.y * 64;
    int tid = threadIdx.x;
    int tm = (tid >> 4) * 4;
    int tn = (tid & 15) * 8;
    // fused q-mean: 16 d's for one row
    int m_ = tid >> 2, dq = (tid & 3) * 16;
    float4 qmr[4];
    {
        const float* qp = q_flat + (size_t)(bm + m_) * HD_ + dq;
#pragma unroll
        for (int qq = 0; qq < 4; ++qq) {
            float4 s0 = {0.f, 0.f, 0.f, 0.f};
#pragma unroll
            for (int h = 0; h < 8; ++h) {
                float4 a = *(const float4*)&qp[h * DH_ + qq * 4];
                s0.x += a.x; s0.y += a.y; s0.z += a.z; s0.w += a.w;
            }
            qmr[qq].x = s0.x * 0.125f; qmr[qq].y = s0.y * 0.125f;
            qmr[qq].z = s0.z * 0.125f; qmr[qq].w = s0.w * 0.125f;
        }
    }
    float acc[4][8] = {};
    for (int kc = 0; kc < 2; ++kc) {
        if (kc) __syncthreads();
        // stage Qs from registers (threads whose dq-half matches kc)
        if ((dq >> 5) == kc) {
#pragma unroll
            for (int qq = 0; qq < 4; ++qq) {
                int dl = dq - kc * 32 + qq * 4;
                int s = (dl >> 2) & 7;
                int mc = (((m_ >> 2) ^ s) << 2) + (m_ & 3);
                Qs[dl+0][mc] = qmr[qq].x; Qs[dl+1][mc] = qmr[qq].y;
                Qs[dl+2][mc] = qmr[qq].z; Qs[dl+3][mc] = qmr[qq].w;
            }
        }
#pragma unroll
        for (int p = 0; p < 4; ++p) {
            int i4 = tid * 4 + p * 1024;
            int n = i4 >> 5, d = i4 & 31;
            float4 a = *(const float4*)&mkeys[(size_t)(chunk0 + bn + n) * DH_ + kc * 32 + d];
            int s = (d >> 2) & 7;
            int nc = (((n >> 2) ^ s) << 2) + (n & 3);
            Ks[d+0][nc] = a.x; Ks[d+1][nc] = a.y; Ks[d+2][nc] = a.z; Ks[d+3][nc] = a.w;
        }
        __syncthreads();
#pragma unroll 8
        for (int d = 0; d < 32; ++d) {
            int s = (d >> 2) & 7;
            int tmw = ((tm >> 2) ^ s) << 2;
            int b0i = ((tn >> 2) ^ s) << 2;
            int b1i = (((tn >> 2) + 1) ^ s) << 2;
            float4 a4 = *(const float4*)&Qs[d][tmw];
            float4 b0 = *(const float4*)&Ks[d][b0i];
            float4 b1 = *(const float4*)&Ks[d][b1i];
            float av[4] = {a4.x, a4.y, a4.z, a4.w};
            float bv[8] = {b0.x, b0.y, b0.z, b0.w, b1.x, b1.y, b1.z, b1.w};
#pragma unroll
            for (int x = 0; x < 4; ++x)
#pragma unroll
                for (int y = 0; y < 8; ++y) acc[x][y] += av[x] * bv[y];
        }
    }
#pragma unroll
    for (int x = 0; x < 4; ++x) {
        float* cp = &selc[(size_t)(bm + tm + x) * ld + bn + tn];
        float4 r0, r1;
        r0.x = acc[x][0]; r0.y = acc[x][1]; r0.z = acc[x][2]; r0.w = acc[x][3];
        r1.x = acc[x][4]; r1.y = acc[x][5]; r1.z = acc[x][6]; r1.w = acc[x][7];
        *(float4*)cp = r0; *(float4*)(cp + 4) = r1;
    }
    {
        int tile = (chunk0 + bn) >> 7;
#pragma unroll
        for (int x = 0; x < 4; ++x) {
            float m = acc[x][0];
#pragma unroll
            for (int y = 1; y < 8; ++y) m = fmaxf(m, acc[x][y]);
#pragma unroll
            for (int o = 1; o < 16; o <<= 1) m = fmaxf(m, __shfl_xor(m, o));
            if ((tid & 15) == 0) tmax[(size_t)(bm + tm + x) * NTILE_ + tile] = m;
        }
    }
}

// ---------------- bitonic shuffle networks (64 lanes) ----------------
__device__ __forceinline__ float awm_sort64_f32(float x, int l) {
#pragma unroll
    for (int k = 2; k <= 64; k <<= 1) {
#pragma unroll
        for (int j = k >> 1; j > 0; j >>= 1) {
            float y = __shfl_xor(x, j);
            bool takeMax = (((l & k) == 0) == ((l & j) == 0));
            float mx = fmaxf(x, y), mn = fminf(x, y);
            x = takeMax ? mx : mn;
        }
    }
    return x;
}
__device__ __forceinline__ unsigned long long awm_sort64_u64(unsigned long long x, int l) {
#pragma unroll
    for (int k = 2; k <= 64; k <<= 1) {
#pragma unroll
        for (int j = k >> 1; j > 0; j >>= 1) {
            unsigned long long y = __shfl_xor(x, j);
            bool takeMax = (((l & k) == 0) == ((l & j) == 0));
            unsigned long long mx = x > y ? x : y;
            unsigned long long mn = x > y ? y : x;
            x = takeMax ? mx : mn;
        }
    }
    return x;
}
__device__ __forceinline__ unsigned long long awm_merge64_u64(unsigned long long x, int l) {
#pragma unroll
    for (int j = 32; j > 0; j >>= 1) {
        unsigned long long y = __shfl_xor(x, j);
        bool takeMax = ((l & j) == 0);
        unsigned long long mx = x > y ? x : y;
        unsigned long long mn = x > y ? y : x;
        x = takeMax ? mx : mn;
    }
    return x;
}

__device__ __forceinline__ unsigned awm_ordkey(float f) {
    unsigned u = __float_as_uint(f);
    return u ^ ((unsigned)((int)u >> 31) | 0x80000000u);
}

// ---------------- tile-max filtered exact top-32 (full-width mode) ----------------
__global__ __launch_bounds__(256) void awm_selfilter_kernel(
    const float* __restrict__ selc, const float* __restrict__ tmax,
    int* __restrict__ topidx) {
    int r = blockIdx.x;
    int tid = threadIdx.x;
    int w = tid >> 6, l = tid & 63;
    __shared__ int tlist[NTILE_];
    __shared__ int ctrs[2];
    __shared__ unsigned long long cand[CCAP_];
    __shared__ unsigned long long wtop[128];
    if (tid < 2) ctrs[tid] = 0;
    float4 m4 = *(const float4*)&tmax[(size_t)r * NTILE_ + (l << 2)];
    float lm = fmaxf(fmaxf(m4.x, m4.y), fmaxf(m4.z, m4.w));
    float sx = awm_sort64_f32(lm, l);
    float s = __shfl(sx, 31);
    __syncthreads();
    {
        float mt = tmax[(size_t)r * NTILE_ + tid];
        if (mt >= s) { int p = atomicAdd(&ctrs[0], 1); tlist[p] = tid; }
    }
    __syncthreads();
    int nt = ctrs[0];
    for (int i = tid; i < nt * 32; i += 256) {
        int tile = tlist[i >> 5];
        int col = (tile << 7) + ((i & 31) << 2);
        float4 v4 = *(const float4*)&selc[(size_t)r * NMEM_ + col];
        float fv[4] = {v4.x, v4.y, v4.z, v4.w};
#pragma unroll
        for (int c2 = 0; c2 < 4; ++c2) {
            if (fv[c2] >= s) {
                int p = atomicAdd(&ctrs[1], 1);
                if (p < CCAP_)
                    cand[p] = ((unsigned long long)awm_ordkey(fv[c2]) << 32)
                            | (unsigned long long)(0xFFFFFFFFu - (unsigned)(col + c2));
            }
        }
    }
    __syncthreads();
    int ne = ctrs[1]; if (ne > CCAP_) ne = CCAP_;
    int nch = (ne + 63) >> 6;
    unsigned long long run = 0ull;
    for (int c = w; c < nch; c += 4) {
        int j = (c << 6) + l;
        unsigned long long xx = (j < ne) ? cand[j] : 0ull;
        xx = awm_sort64_u64(xx, l);
        unsigned long long rv = __shfl(xx, 63 - l);
        run = (run > rv) ? run : rv;
        run = awm_merge64_u64(run, l);
    }
    if (l < 32) wtop[w * 32 + l] = run;
    __syncthreads();
    if (w == 0) {
        unsigned long long a = (l < 32) ? wtop[l] : wtop[32 + (63 - l)];
        a = awm_merge64_u64(a, l);
        unsigned long long b = (l < 32) ? wtop[64 + l] : wtop[96 + (63 - l)];
        b = awm_merge64_u64(b, l);
        unsigned long long z = (l < 32) ? a : __shfl(b, 63 - l);
        z = awm_merge64_u64(z, l);
        if (l < 32)
            topidx[r * TOPK_ + l] =
                (int)(0xFFFFFFFFu - (unsigned)(z & 0xFFFFFFFFull));
    }
}

// ---------------- histogram radix-select (chunked fallback) ----------------
__global__ __launch_bounds__(256) void awm_seltop_kernel(
    const float* __restrict__ selc, int ld, int chunk_arg,
    float* __restrict__ cand_val, int* __restrict__ cand_idx) {
    int r = blockIdx.x;
    int chunk = (chunk_arg >= 0) ? chunk_arg : (int)blockIdx.y;
    int col0 = (ld == NMEM_) ? chunk * SELC_ : 0;
    int tid = threadIdx.x;
    __shared__ unsigned hist[4096];
    __shared__ float eqv[EQCAP_];
    __shared__ unsigned eqi[EQCAP_];
    __shared__ float abv_v[32];
    __shared__ unsigned abv_i[32];
    __shared__ int ctrs[2];
    __shared__ int binfo[1];
    for (int i = tid; i < 4096; i += 256) hist[i] = 0u;
    if (tid < 2) ctrs[tid] = 0;
    if (tid == 0) binfo[0] = 0;
    __syncthreads();
    const float* src = selc + (size_t)r * ld + col0;
    float4 vv[8];
#pragma unroll
    for (int p = 0; p < 8; ++p)
        vv[p] = *(const float4*)&src[(tid << 2) + (p << 10)];
#pragma unroll
    for (int p = 0; p < 8; ++p) {
        atomicAdd(&hist[awm_ordkey(vv[p].x) >> 20], 1u);
        atomicAdd(&hist[awm_ordkey(vv[p].y) >> 20], 1u);
        atomicAdd(&hist[awm_ordkey(vv[p].z) >> 20], 1u);
        atomicAdd(&hist[awm_ordkey(vv[p].w) >> 20], 1u);
    }
    __syncthreads();
    if (tid < 64) {
        int lane = tid;
        unsigned s = 0;
        for (int j = 0; j < 64; ++j)
            s += hist[(lane << 6) + ((j + lane) & 63)];
        unsigned suf = s;
#pragma unroll
        for (int off = 1; off < 64; off <<= 1) {
            unsigned t2 = __shfl_down(suf, off);
            suf += (lane + off < 64) ? t2 : 0u;
        }
        unsigned nd = __shfl_down(suf, 1);
        unsigned nxt = (lane == 63) ? 0u : nd;
        bool cross = (suf >= (unsigned)TOPK_) && (nxt < (unsigned)TOPK_);
        unsigned long long mc = __ballot(cross ? 1 : 0);
        int sstar = (mc == 0ull) ? 63 : (int)__builtin_ctzll(mc);
        unsigned above_super = (mc == 0ull) ? 0u : __shfl(nxt, sstar);
        unsigned suf2 = hist[(sstar << 6) + lane];
#pragma unroll
        for (int off = 1; off < 64; off <<= 1) {
            unsigned t2 = __shfl_down(suf2, off);
            suf2 += (lane + off < 64) ? t2 : 0u;
        }
        unsigned tot = suf2 + above_super;
        unsigned nd2 = __shfl_down(tot, 1);
        unsigned nxt2 = (lane == 63) ? above_super : nd2;
        bool cross2 = (tot >= (unsigned)TOPK_) && (nxt2 < (unsigned)TOPK_);
        if (cross2) binfo[0] = (sstar << 6) + lane;
    }
    __syncthreads();
    int theta = binfo[0];
    int gbase = chunk * SELC_;
#pragma unroll
    for (int p = 0; p < 8; ++p) {
        float fv[4] = {vv[p].x, vv[p].y, vv[p].z, vv[p].w};
#pragma unroll
        for (int c = 0; c < 4; ++c) {
            int bin = (int)(awm_ordkey(fv[c]) >> 20);
            if (bin >= theta) {
                unsigned li = (unsigned)((tid << 2) + (p << 10) + c);
                if (bin > theta) {
                    int pos = atomicAdd(&ctrs[0], 1);
                    if (pos < 32) { abv_v[pos] = fv[c]; abv_i[pos] = li; }
                } else {
                    int pos = atomicAdd(&ctrs[1], 1);
                    if (pos < EQCAP_) { eqv[pos] = fv[c]; eqi[pos] = li; }
                }
            }
        }
    }
    __syncthreads();
    if (tid < 64) {
        int lane = tid;
        int na = ctrs[0]; if (na > TOPK_) na = TOPK_;
        int ne = ctrs[1]; if (ne > EQCAP_) ne = EQCAP_;
        float* cvp = cand_val + (size_t)r * 128 + chunk * 32;
        int* cip = cand_idx + (size_t)r * 128 + chunk * 32;
        if (lane < na) { cvp[lane] = abv_v[lane]; cip[lane] = gbase + (int)abv_i[lane]; }
        int need = TOPK_ - na;
        unsigned deadm = 0u;
        for (int it = 0; it < need; ++it) {
            float bv = -INFINITY; unsigned bi = 0xFFFFFFFFu; int bs = -1;
            int jj = 0;
            for (int j = lane; j < ne; j += 64, ++jj) {
                if (!((deadm >> jj) & 1u)) {
                    float vq = eqv[j]; unsigned iq = eqi[j];
                    if (vq > bv || (vq == bv && iq < bi)) { bv = vq; bi = iq; bs = j; }
                }
            }
#pragma unroll
            for (int off = 32; off > 0; off >>= 1) {
                float ov = __shfl_xor(bv, off);
                unsigned oi = __shfl_xor(bi, off);
                int os = __shfl_xor(bs, off);
                if (ov > bv || (ov == bv && oi < bi)) { bv = ov; bi = oi; bs = os; }
            }
            if (lane == 0) {
                int gi = (bi == 0xFFFFFFFFu) ? gbase : (gbase + (int)bi);
                cvp[na + it] = bv; cip[na + it] = gi;
            }
            if (bs >= 0 && (bs & 63) == lane) deadm |= (1u << (bs >> 6));
        }
    }
}

// ---------------- merge 4x32 candidates -> global top-32 (fallback only) ----------------
__global__ __launch_bounds__(64) void awm_merge_kernel(
    const float* __restrict__ cand_val, const int* __restrict__ cand_idx,
    int* __restrict__ topidx) {
    int r = blockIdx.x;
    int lane = threadIdx.x;
    float v0 = cand_val[(size_t)r * 128 + lane];
    float v1 = cand_val[(size_t)r * 128 + 64 + lane];
    int i0 = cand_idx[(size_t)r * 128 + lane];
    int i1 = cand_idx[(size_t)r * 128 + 64 + lane];
    for (int it = 0; it < TOPK_; ++it) {
        float v; int ix;
        if (v0 > v1 || (v0 == v1 && i0 < i1)) { v = v0; ix = i0; } else { v = v1; ix = i1; }
#pragma unroll
        for (int off = 32; off > 0; off >>= 1) {
            float ov = __shfl_xor(v, off);
            int oi = __shfl_xor(ix, off);
            if (ov > v || (ov == v && oi < ix)) { v = ov; ix = oi; }
        }
        if (lane == 0) topidx[r * TOPK_ + it] = ix;
        if (ix == i0) v0 = -INFINITY;
        else if (ix == i1) v1 = -INFINITY;
    }
}

// ---------------- hidden proj GEMM: hq = q@W1q + bs1 (y=0), hkc = k@W1k (y=1) ----------------
__global__ __launch_bounds__(256) void awm_hid_kernel(
    const float* __restrict__ q_flat, const float* __restrict__ k_flat,
    const float* __restrict__ Ws1, const float* __restrict__ bs1,
    float* __restrict__ hq, float* __restrict__ hkc) {
    int isK = blockIdx.y;
    int bm = blockIdx.x * 32;
    int tid = threadIdx.x;
    __shared__ float As[64][34];
    __shared__ float Ws_s[64][132];
    const float* src = isK ? k_flat : q_flat;
    const float* W = Ws1 + (isK ? (size_t)DH_ * HID_ : 0);
    {
        int m = tid >> 3, kq = (tid & 7) * 8;
        int rho = bm + m;
        int bh = rho >> 8, t = rho & 255;
        int b = bh >> 3, h = bh & 7;
        const float* sp = src + (size_t)(b * T_ + t) * HD_ + h * DH_ + kq;
        float4 a = *(const float4*)sp;
        float4 c = *(const float4*)(sp + 4);
        As[kq+0][m] = a.x; As[kq+1][m] = a.y; As[kq+2][m] = a.z; As[kq+3][m] = a.w;
        As[kq+4][m] = c.x; As[kq+5][m] = c.y; As[kq+6][m] = c.z; As[kq+7][m] = c.w;
    }
    for (int i = tid; i < 64 * HID_ / 4; i += 256) {
        int k = (i * 4) >> 7, f = (i * 4) & 127;
        *(float4*)&Ws_s[k][f] = *(const float4*)&W[(size_t)k * HID_ + f];
    }
    __syncthreads();
    int tm = (tid >> 4) * 2, tn = (tid & 15) * 8;
    float acc[2][8] = {};
#pragma unroll 8
    for (int k = 0; k < DH_; ++k) {
        float2 a2 = *(const float2*)&As[k][tm];
        float4 b0 = *(const float4*)&Ws_s[k][tn];
        float4 b1 = *(const float4*)&Ws_s[k][tn + 4];
        float av[2] = {a2.x, a2.y};
        float bv[8] = {b0.x, b0.y, b0.z, b0.w, b1.x, b1.y, b1.z, b1.w};
#pragma unroll
        for (int x = 0; x < 2; ++x)
#pragma unroll
            for (int y = 0; y < 8; ++y) acc[x][y] += av[x] * bv[y];
    }
    float* out = isK ? hkc : hq;
#pragma unroll
    for (int x = 0; x < 2; ++x) {
        int rho = bm + tm + x;
        float vv[8];
#pragma unroll
        for (int y = 0; y < 8; ++y)
            vv[y] = acc[x][y] + (isK ? 0.f : bs1[tn + y]);
        float4 r0, r1;
        r0.x = vv[0]; r0.y = vv[1]; r0.z = vv[2]; r0.w = vv[3];
        r1.x = vv[4]; r1.y = vv[5]; r1.z = vv[6]; r1.w = vv[7];
        float* op = out + (size_t)rho * HID_ + tn;
        *(float4*)op = r0; *(float4*)(op + 4) = r1;
    }
}

// ---------------- fused: hk_mem + mem scores, one block per (b,t) ----------------
__global__ __launch_bounds__(256) void awm_smem_kernel(
    const float* __restrict__ hq, const float* __restrict__ mkeys,
    const int* __restrict__ topidx, const float* __restrict__ Ws1,
    const float* __restrict__ Ws2, float* __restrict__ smem_out) {
    int bt = blockIdx.x;
    int b = bt >> 8, t = bt & 255;
    int tid = threadIdx.x;
    __shared__ float W1k_s[32][132];
    __shared__ float mk_s[64][36];
    __shared__ float hkm_s[32][133];
    __shared__ float hq_s[8][132];
    __shared__ float w2_s[HID_];
    __shared__ int key_s[TOPK_];
    {
        int h = tid >> 5, fq = (tid & 31) * 4;
        *(float4*)&hq_s[h][fq] =
            *(const float4*)&hq[((size_t)(b * H_ + h) * T_ + t) * HID_ + fq];
    }
    if (tid < HID_) w2_s[tid] = Ws2[tid];
    if (tid < TOPK_) key_s[tid] = topidx[bt * TOPK_ + tid];
    __syncthreads();
    {
        int j = tid >> 3, kq = (tid & 7) * 8;
        const float* sp = mkeys + (size_t)key_s[j] * DH_ + kq;
        float4 a = *(const float4*)sp;
        float4 c = *(const float4*)(sp + 4);
        mk_s[kq+0][j] = a.x; mk_s[kq+1][j] = a.y; mk_s[kq+2][j] = a.z; mk_s[kq+3][j] = a.w;
        mk_s[kq+4][j] = c.x; mk_s[kq+5][j] = c.y; mk_s[kq+6][j] = c.z; mk_s[kq+7][j] = c.w;
    }
    int j0 = (tid >> 5) * 4, f0 = (tid & 31) * 4;
    float acc[4][4] = {};
    for (int kc = 0; kc < 2; ++kc) {
        __syncthreads();
        for (int i = tid; i < 32 * HID_ / 4; i += 256) {
            int k = (i * 4) >> 7, f = (i * 4) & 127;
            *(float4*)&W1k_s[k][f] =
                *(const float4*)&Ws1[(size_t)(DH_ + kc * 32 + k) * HID_ + f];
        }
        __syncthreads();
#pragma unroll 8
        for (int k = 0; k < 32; ++k) {
            float4 a4 = *(const float4*)&mk_s[kc * 32 + k][j0];
            float4 b4 = *(const float4*)&W1k_s[k][f0];
            float av[4] = {a4.x, a4.y, a4.z, a4.w};
            float bv[4] = {b4.x, b4.y, b4.z, b4.w};
#pragma unroll
            for (int x = 0; x < 4; ++x)
#pragma unroll
                for (int y = 0; y < 4; ++y) acc[x][y] += av[x] * bv[y];
        }
    }
#pragma unroll
    for (int x = 0; x < 4; ++x)
#pragma unroll
        for (int y = 0; y < 4; ++y) hkm_s[j0 + x][f0 + y] = acc[x][y];
    __syncthreads();
    int h = tid >> 5, j = tid & 31;
    float sacc = 0.f;
#pragma unroll 8
    for (int f = 0; f < HID_; ++f) {
        float u = hq_s[h][f] + hkm_s[j][f];
        sacc += fmaxf(u, 0.f) * w2_s[f];
    }
    smem_out[((size_t)(b * H_ + h) * T_ + t) * TOPK_ + j] = sacc;
}

// ---------------- fused ctx scores + softmax + PV + gate; block = (b,h, 16-t tile), 512 thr ----------------
__global__ __launch_bounds__(512) void awm_attn2_kernel(
    const float* __restrict__ hq, const float* __restrict__ hkc,
    const float* __restrict__ smem_in, const float* __restrict__ v_flat,
    const float* __restrict__ mem_values, const int* __restrict__ topidx,
    const float* __restrict__ Ws2, const float* __restrict__ gates,
    float* __restrict__ outg) {
    int tb = blockIdx.x;       // 0..15
    int bh = blockIdx.y;
    int b = bh >> 3, h = bh & 7;
    int tbase = tb * TT_;
    int tid = threadIdx.x;     // 0..511
    __shared__ float hq_s[HID_][TT_ + 2];   // [128][18]
    __shared__ float hk_s[32][260];
    __shared__ float sc[TT_][292];
    __shared__ float w2_s[HID_];
    __shared__ int idx_s[TT_][TOPK_];
    {
        int t = tid >> 5, fq = (tid & 31) * 4;
        float4 a = *(const float4*)&hq[((size_t)bh * T_ + tbase + t) * HID_ + fq];
        hq_s[fq+0][t] = a.x; hq_s[fq+1][t] = a.y; hq_s[fq+2][t] = a.z; hq_s[fq+3][t] = a.w;
    }
    if (tid < HID_) w2_s[tid] = Ws2[tid];
    {
        int t = tid >> 5, j = tid & 31;
        sc[t][256 + j] = smem_in[((size_t)bh * T_ + tbase + t) * TOPK_ + j];
        idx_s[t][j] = topidx[((size_t)b * T_ + tbase + t) * TOPK_ + j];
    }
    int t0 = (tid >> 6) * 2, s0 = (tid & 63) * 4;
    float acc[2][4] = {};
    for (int fc = 0; fc < 4; ++fc) {
        __syncthreads();
        {   // stage hk_s[32f][256s]: 4 float4/thread
            int f4 = (tid & 7) * 4, sr = tid >> 3;   // sr 0..63
#pragma unroll
            for (int p = 0; p < 4; ++p) {
                int s = sr + p * 64;
                float4 a = *(const float4*)&hkc[((size_t)bh * T_ + s) * HID_ + fc * 32 + f4];
                hk_s[f4+0][s] = a.x; hk_s[f4+1][s] = a.y; hk_s[f4+2][s] = a.z; hk_s[f4+3][s] = a.w;
            }
        }
        __syncthreads();
#pragma unroll 8
        for (int f = 0; f < 32; ++f) {
            float2 a2 = *(const float2*)&hq_s[fc * 32 + f][t0];
            float4 b4 = *(const float4*)&hk_s[f][s0];
            float w2f = w2_s[fc * 32 + f];
            float av[2] = {a2.x, a2.y};
            float bv[4] = {b4.x, b4.y, b4.z, b4.w};
#pragma unroll
            for (int x = 0; x < 2; ++x)
#pragma unroll
                for (int y = 0; y < 4; ++y)
                    acc[x][y] += fmaxf(av[x] + bv[y], 0.f) * w2f;
        }
    }
    {
        float4 r0, r1;
        r0.x = acc[0][0]; r0.y = acc[0][1]; r0.z = acc[0][2]; r0.w = acc[0][3];
        r1.x = acc[1][0]; r1.y = acc[1][1]; r1.z = acc[1][2]; r1.w = acc[1][3];
        *(float4*)&sc[t0][s0] = r0;
        *(float4*)&sc[t0 + 1][s0] = r1;
    }
    __syncthreads();
    {
        int t = tid >> 5, l = tid & 31;
        float mx = -INFINITY;
#pragma unroll
        for (int k = 0; k < 9; ++k) mx = fmaxf(mx, sc[t][l + 32 * k]);
#pragma unroll
        for (int off = 16; off > 0; off >>= 1) mx = fmaxf(mx, __shfl_xor(mx, off, 32));
        float sum = 0.f;
#pragma unroll
        for (int k = 0; k < 9; ++k) {
            float e = expf(sc[t][l + 32 * k] - mx);
            sc[t][l + 32 * k] = e;
            sum += e;
        }
#pragma unroll
        for (int off = 16; off > 0; off >>= 1) sum += __shfl_xor(sum, off, 32);
        float inv = 1.f / sum;
#pragma unroll
        for (int k = 0; k < 9; ++k) sc[t][l + 32 * k] *= inv;
    }
    __syncthreads();
    {
        int g = tid >> 6, l = tid & 63;   // g 0..7
        int ta = 2 * g, tbb = 2 * g + 1;
        const float* vb = v_flat + (size_t)b * T_ * HD_ + h * DH_ + l;
        float a0 = 0.f, a1 = 0.f;
#pragma unroll 8
        for (int s = 0; s < T_; ++s) {
            float vv = vb[(size_t)s * HD_];
            a0 += sc[ta][s] * vv;
            a1 += sc[tbb][s] * vv;
        }
#pragma unroll 4
        for (int j = 0; j < TOPK_; ++j) {
            a0 += sc[ta][256 + j] * mem_values[(size_t)idx_s[ta][j] * DH_ + l];
            a1 += sc[tbb][256 + j] * mem_values[(size_t)idx_s[tbb][j] * DH_ + l];
        }
        float g0 = gates[(size_t)(b * T_ + tbase + ta) * H_ + h];
        float g1v = gates[(size_t)(b * T_ + tbase + tbb) * H_ + h];
        outg[(size_t)(b * T_ + tbase + ta) * HD_ + h * DH_ + l] = a0 * g0;
        outg[(size_t)(b * T_ + tbase + tbb) * HD_ + h * DH_ + l] = a1 * g1v;
    }
}

extern "C" void kernel_launch(void* const* d_in, const int* in_sizes, int n_in,
                              void* d_out, int out_size, void* d_ws, size_t ws_size,
                              hipStream_t stream) {
    (void)in_sizes; (void)n_in; (void)out_size;
    const float* x    = (const float*)d_in[0];
    const float* Wq   = (const float*)d_in[1];
    const float* Wk   = (const float*)d_in[2];
    const float* Wv   = (const float*)d_in[3];
    const float* Wo   = (const float*)d_in[4];
    const float* Wg1  = (const float*)d_in[5];
    const float* bg1  = (const float*)d_in[6];
    const float* Wg2  = (const float*)d_in[7];
    const float* bg2  = (const float*)d_in[8];
    const float* Ws1  = (const float*)d_in[9];
    const float* bs1  = (const float*)d_in[10];
    const float* Ws2  = (const float*)d_in[11];
    const float* mk   = (const float*)d_in[13];
    const float* mv   = (const float*)d_in[14];
    float* y = (float*)d_out;

    float* w = (float*)d_ws;
    size_t off = 0;
    float* q_flat = w + off; off += (size_t)BT_ * HD_;
    float* k_flat = w + off; off += (size_t)BT_ * HD_;
    float* v_flat = w + off; off += (size_t)BT_ * HD_;
    float* gates  = w + off; off += (size_t)BT_ * H_;
    float* hq     = w + off; off += (size_t)B_ * H_ * T_ * HID_;
    float* hkc    = w + off; off += (size_t)B_ * H_ * T_ * HID_;
    float* smemb  = w + off; off += (size_t)B_ * H_ * T_ * TOPK_;
    float* outg   = w + off; off += (size_t)BT_ * HD_;
    float* cand_v = w + off; off += (size_t)BT_ * 128;
    int*   cand_i = (int*)(w + off); off += (size_t)BT_ * 128;
    int*   topidx = (int*)(w + off); off += (size_t)BT_ * TOPK_;
    float* tmax   = w + off; off += (size_t)BT_ * NTILE_;
    float* selc   = w + off;
    int fullw = (ws_size >= (off + (size_t)BT_ * NMEM_) * sizeof(float));

    dim3 thr256(256);
    awm_qkvg_kernel<<<dim3(8, 16, 4), thr256, 0, stream>>>(
        x, Wq, Wk, Wv, Wg1, bg1, Wg2, bg2, q_flat, k_flat, v_flat, gates);
    if (fullw) {
        awm_selgemm_kernel<<<dim3(NMEM_ / 128, BT_ / 64), thr256, 0, stream>>>(
            q_flat, mk, selc, tmax, 0, NMEM_);
        awm_selfilter_kernel<<<dim3(BT_), thr256, 0, stream>>>(selc, tmax, topidx);
    } else {
        for (int c = 0; c < NCHUNK_; ++c) {
            awm_selgemm_kernel<<<dim3(SELC_ / 128, BT_ / 64), thr256, 0, stream>>>(
                q_flat, mk, selc, tmax, c * SELC_, SELC_);
            awm_seltop_kernel<<<dim3(BT_, 1), thr256, 0, stream>>>(
                selc, SELC_, c, cand_v, cand_i);
        }
        awm_merge_kernel<<<dim3(BT_), dim3(64), 0, stream>>>(cand_v, cand_i, topidx);
    }
    awm_hid_kernel<<<dim3(B_ * H_ * T_ / 32, 2), thr256, 0, stream>>>(
        q_flat, k_flat, Ws1, bs1, hq, hkc);
    awm_smem_kernel<<<dim3(BT_), thr256, 0, stream>>>(hq, mk, topidx, Ws1, Ws2, smemb);
    awm_attn2_kernel<<<dim3(T_ / TT_, B_ * H_), dim3(512), 0, stream>>>(
        hq, hkc, smemb, v_flat, mv, topidx, Ws2, gates, outg);
    awm_out_kernel<<<dim3(8, 16), thr256, 0, stream>>>(outg, Wo, y);
}

// Round 10
// 144.648 us; speedup vs baseline: 1.0501x; 1.0501x over previous
//
#include <hip/hip_runtime.h>
#include <math.h>

#define B_ 2
#define T_ 256
#define DM_ 512
#define H_ 8
#define DH_ 64
#define HID_ 128
#define GH_ 64
#define NMEM_ 32768
#define TOPK_ 32
#define BT_ (B_*T_)      // 512
#define HD_ (H_*DH_)     // 512
#define SELC_ 8192
#define NCHUNK_ (NMEM_/SELC_)  // 4
#define TT_ 16           // t-tile for fused attention (512 threads)
#define EQCAP_ 512
#define NTILE_ 256       // NMEM_/128
#define CCAP_ 2048

// ---------------- fused QKV + gelu-gate projections ----------------
__global__ __launch_bounds__(256) void awm_qkvg_kernel(
    const float* __restrict__ x,
    const float* __restrict__ Wq, const float* __restrict__ Wk, const float* __restrict__ Wv,
    const float* __restrict__ Wg1, const float* __restrict__ bg1,
    const float* __restrict__ Wg2, const float* __restrict__ bg2,
    float* __restrict__ q, float* __restrict__ k, float* __restrict__ v,
    float* __restrict__ gates) {
    int z = blockIdx.z;
    if (z == 3 && blockIdx.x != 0) return;
    const float* W = (z == 0) ? Wq : (z == 1) ? Wk : (z == 2) ? Wv : Wg1;
    float* C = (z == 0) ? q : (z == 1) ? k : v;
    const int N = (z == 3) ? GH_ : HD_;
    __shared__ float As[32][34];
    __shared__ float Bs[32][68];
    int bm = blockIdx.y * 32, bn = blockIdx.x * 64;
    int tid = threadIdx.x;
    int tm = (tid >> 4) * 2, tn = (tid & 15) * 4;
    float acc[2][4] = {};
    for (int k0 = 0; k0 < DM_; k0 += 32) {
        {
            int m = tid >> 3, kk = (tid & 7) * 4;
            float4 a = *(const float4*)&x[(size_t)(bm + m) * DM_ + k0 + kk];
            As[kk+0][m] = a.x; As[kk+1][m] = a.y; As[kk+2][m] = a.z; As[kk+3][m] = a.w;
#pragma unroll
            for (int p = 0; p < 2; ++p) {
                int idx = tid * 4 + p * 1024;
                int kb = idx >> 6, n = idx & 63;
                *(float4*)&Bs[kb][n] = *(const float4*)&W[(size_t)(k0 + kb) * N + bn + n];
            }
        }
        __syncthreads();
#pragma unroll
        for (int kk = 0; kk < 32; ++kk) {
            float2 a2 = *(const float2*)&As[kk][tm];
            float4 b4 = *(const float4*)&Bs[kk][tn];
            acc[0][0] += a2.x * b4.x; acc[0][1] += a2.x * b4.y;
            acc[0][2] += a2.x * b4.z; acc[0][3] += a2.x * b4.w;
            acc[1][0] += a2.y * b4.x; acc[1][1] += a2.y * b4.y;
            acc[1][2] += a2.y * b4.z; acc[1][3] += a2.y * b4.w;
        }
        __syncthreads();
    }
    if (z < 3) {
#pragma unroll
        for (int xr = 0; xr < 2; ++xr) {
            float4 r; r.x = acc[xr][0]; r.y = acc[xr][1]; r.z = acc[xr][2]; r.w = acc[xr][3];
            *(float4*)&C[(size_t)(bm + tm + xr) * HD_ + bn + tn] = r;
        }
    } else {
#pragma unroll
        for (int xr = 0; xr < 2; ++xr)
#pragma unroll
            for (int y = 0; y < 4; ++y) {
                float vv = acc[xr][y] + bg1[tn + y];
                float u = 0.7978845608028654f * (vv + 0.044715f * vv * vv * vv);
                Bs[tm + xr][tn + y] = 0.5f * vv * (1.f + tanhf(u));
            }
        float* wg = &As[0][0];
        for (int i = tid; i < GH_ * H_; i += 256) wg[i] = Wg2[i];
        __syncthreads();
        int r = tid >> 3, hh = tid & 7;
        float acg = bg2[hh];
#pragma unroll
        for (int j = 0; j < GH_; ++j) acg += Bs[r][j] * wg[j * H_ + hh];
        gates[(size_t)(bm + r) * H_ + hh] = 1.f / (1.f + expf(-acg));
    }
}

// ---------------- output projection: y = outg @ Wo ----------------
__global__ __launch_bounds__(256) void awm_out_kernel(
    const float* __restrict__ A, const float* __restrict__ W, float* __restrict__ C) {
    __shared__ float As[32][34];
    __shared__ float Bs[32][68];
    int bm = blockIdx.y * 32, bn = blockIdx.x * 64;
    int tid = threadIdx.x;
    int tm = (tid >> 4) * 2, tn = (tid & 15) * 4;
    float acc[2][4] = {};
    for (int k0 = 0; k0 < HD_; k0 += 32) {
        {
            int m = tid >> 3, kk = (tid & 7) * 4;
            float4 a = *(const float4*)&A[(size_t)(bm + m) * HD_ + k0 + kk];
            As[kk+0][m] = a.x; As[kk+1][m] = a.y; As[kk+2][m] = a.z; As[kk+3][m] = a.w;
#pragma unroll
            for (int p = 0; p < 2; ++p) {
                int idx = tid * 4 + p * 1024;
                int kb = idx >> 6, n = idx & 63;
                *(float4*)&Bs[kb][n] = *(const float4*)&W[(size_t)(k0 + kb) * DM_ + bn + n];
            }
        }
        __syncthreads();
#pragma unroll
        for (int kk = 0; kk < 32; ++kk) {
            float2 a2 = *(const float2*)&As[kk][tm];
            float4 b4 = *(const float4*)&Bs[kk][tn];
            acc[0][0] += a2.x * b4.x; acc[0][1] += a2.x * b4.y;
            acc[0][2] += a2.x * b4.z; acc[0][3] += a2.x * b4.w;
            acc[1][0] += a2.y * b4.x; acc[1][1] += a2.y * b4.y;
            acc[1][2] += a2.y * b4.z; acc[1][3] += a2.y * b4.w;
        }
        __syncthreads();
    }
#pragma unroll
    for (int xr = 0; xr < 2; ++xr) {
        float4 r; r.x = acc[xr][0]; r.y = acc[xr][1]; r.z = acc[xr][2]; r.w = acc[xr][3];
        *(float4*)&C[(size_t)(bm + tm + xr) * DM_ + bn + tn] = r;
    }
}

// ---------------- q_for_mem: mean over heads ----------------
__global__ void awm_qmean_kernel(const float* __restrict__ q_flat, float* __restrict__ qm) {
    int i = blockIdx.x * 256 + threadIdx.x;
    if (i >= BT_ * DH_) return;
    int r = i / DH_, d = i % DH_;
    float acc = 0.f;
#pragma unroll
    for (int h = 0; h < H_; ++h) acc += q_flat[r * HD_ + h * DH_ + d];
    qm[i] = acc * 0.125f;
}

// ---------------- sel GEMM + per-(row,128-tile) max ----------------
__global__ __launch_bounds__(256) void awm_selgemm_kernel(
    const float* __restrict__ qm, const float* __restrict__ mkeys,
    float* __restrict__ selc, float* __restrict__ tmax, int chunk0, int ld) {
    __shared__ float Qs[32][68];
    __shared__ float Ks[32][132];
    int bn = blockIdx.x * 128;
    int bm = blockIdx.y * 64;
    int tid = threadIdx.x;
    int tm = (tid >> 4) * 4;
    int tn = (tid & 15) * 8;
    float acc[4][8] = {};
    for (int kc = 0; kc < 2; ++kc) {
        if (kc) __syncthreads();
#pragma unroll
        for (int p = 0; p < 2; ++p) {
            int i4 = tid * 4 + p * 1024;
            int m = i4 >> 5, d = i4 & 31;
            float4 a = *(const float4*)&qm[(size_t)(bm + m) * DH_ + kc * 32 + d];
            int s = (d >> 2) & 7;
            int mc = (((m >> 2) ^ s) << 2) + (m & 3);
            Qs[d+0][mc] = a.x; Qs[d+1][mc] = a.y; Qs[d+2][mc] = a.z; Qs[d+3][mc] = a.w;
        }
#pragma unroll
        for (int p = 0; p < 4; ++p) {
            int i4 = tid * 4 + p * 1024;
            int n = i4 >> 5, d = i4 & 31;
            float4 a = *(const float4*)&mkeys[(size_t)(chunk0 + bn + n) * DH_ + kc * 32 + d];
            int s = (d >> 2) & 7;
            int nc = (((n >> 2) ^ s) << 2) + (n & 3);
            Ks[d+0][nc] = a.x; Ks[d+1][nc] = a.y; Ks[d+2][nc] = a.z; Ks[d+3][nc] = a.w;
        }
        __syncthreads();
#pragma unroll 8
        for (int d = 0; d < 32; ++d) {
            int s = (d >> 2) & 7;
            int tmw = ((tm >> 2) ^ s) << 2;
            int b0i = ((tn >> 2) ^ s) << 2;
            int b1i = (((tn >> 2) + 1) ^ s) << 2;
            float4 a4 = *(const float4*)&Qs[d][tmw];
            float4 b0 = *(const float4*)&Ks[d][b0i];
            float4 b1 = *(const float4*)&Ks[d][b1i];
            float av[4] = {a4.x, a4.y, a4.z, a4.w};
            float bv[8] = {b0.x, b0.y, b0.z, b0.w, b1.x, b1.y, b1.z, b1.w};
#pragma unroll
            for (int x = 0; x < 4; ++x)
#pragma unroll
                for (int y = 0; y < 8; ++y) acc[x][y] += av[x] * bv[y];
        }
    }
#pragma unroll
    for (int x = 0; x < 4; ++x) {
        float* cp = &selc[(size_t)(bm + tm + x) * ld + bn + tn];
        float4 r0, r1;
        r0.x = acc[x][0]; r0.y = acc[x][1]; r0.z = acc[x][2]; r0.w = acc[x][3];
        r1.x = acc[x][4]; r1.y = acc[x][5]; r1.z = acc[x][6]; r1.w = acc[x][7];
        *(float4*)cp = r0; *(float4*)(cp + 4) = r1;
    }
    {
        int tile = (chunk0 + bn) >> 7;
#pragma unroll
        for (int x = 0; x < 4; ++x) {
            float m = acc[x][0];
#pragma unroll
            for (int y = 1; y < 8; ++y) m = fmaxf(m, acc[x][y]);
#pragma unroll
            for (int o = 1; o < 16; o <<= 1) m = fmaxf(m, __shfl_xor(m, o));
            if ((tid & 15) == 0) tmax[(size_t)(bm + tm + x) * NTILE_ + tile] = m;
        }
    }
}

// ---------------- bitonic shuffle networks (64 lanes) ----------------
__device__ __forceinline__ float awm_sort64_f32(float x, int l) {
#pragma unroll
    for (int k = 2; k <= 64; k <<= 1) {
#pragma unroll
        for (int j = k >> 1; j > 0; j >>= 1) {
            float y = __shfl_xor(x, j);
            bool takeMax = (((l & k) == 0) == ((l & j) == 0));
            float mx = fmaxf(x, y), mn = fminf(x, y);
            x = takeMax ? mx : mn;
        }
    }
    return x;
}
__device__ __forceinline__ unsigned long long awm_sort64_u64(unsigned long long x, int l) {
#pragma unroll
    for (int k = 2; k <= 64; k <<= 1) {
#pragma unroll
        for (int j = k >> 1; j > 0; j >>= 1) {
            unsigned long long y = __shfl_xor(x, j);
            bool takeMax = (((l & k) == 0) == ((l & j) == 0));
            unsigned long long mx = x > y ? x : y;
            unsigned long long mn = x > y ? y : x;
            x = takeMax ? mx : mn;
        }
    }
    return x;
}
__device__ __forceinline__ unsigned long long awm_merge64_u64(unsigned long long x, int l) {
#pragma unroll
    for (int j = 32; j > 0; j >>= 1) {
        unsigned long long y = __shfl_xor(x, j);
        bool takeMax = ((l & j) == 0);
        unsigned long long mx = x > y ? x : y;
        unsigned long long mn = x > y ? y : x;
        x = takeMax ? mx : mn;
    }
    return x;
}

__device__ __forceinline__ unsigned awm_ordkey(float f) {
    unsigned u = __float_as_uint(f);
    return u ^ ((unsigned)((int)u >> 31) | 0x80000000u);
}

// ---------------- tile-max filtered exact top-32 (full-width mode) ----------------
__global__ __launch_bounds__(256) void awm_selfilter_kernel(
    const float* __restrict__ selc, const float* __restrict__ tmax,
    int* __restrict__ topidx) {
    int r = blockIdx.x;
    int tid = threadIdx.x;
    int w = tid >> 6, l = tid & 63;
    __shared__ int tlist[NTILE_];
    __shared__ int ctrs[2];
    __shared__ unsigned long long cand[CCAP_];
    __shared__ unsigned long long wtop[128];
    if (tid < 2) ctrs[tid] = 0;
    float4 m4 = *(const float4*)&tmax[(size_t)r * NTILE_ + (l << 2)];
    float lm = fmaxf(fmaxf(m4.x, m4.y), fmaxf(m4.z, m4.w));
    float sx = awm_sort64_f32(lm, l);
    float s = __shfl(sx, 31);
    __syncthreads();
    {
        float mt = tmax[(size_t)r * NTILE_ + tid];
        if (mt >= s) { int p = atomicAdd(&ctrs[0], 1); tlist[p] = tid; }
    }
    __syncthreads();
    int nt = ctrs[0];
    for (int i = tid; i < nt * 32; i += 256) {
        int tile = tlist[i >> 5];
        int col = (tile << 7) + ((i & 31) << 2);
        float4 v4 = *(const float4*)&selc[(size_t)r * NMEM_ + col];
        float fv[4] = {v4.x, v4.y, v4.z, v4.w};
#pragma unroll
        for (int c2 = 0; c2 < 4; ++c2) {
            if (fv[c2] >= s) {
                int p = atomicAdd(&ctrs[1], 1);
                if (p < CCAP_)
                    cand[p] = ((unsigned long long)awm_ordkey(fv[c2]) << 32)
                            | (unsigned long long)(0xFFFFFFFFu - (unsigned)(col + c2));
            }
        }
    }
    __syncthreads();
    int ne = ctrs[1]; if (ne > CCAP_) ne = CCAP_;
    int nch = (ne + 63) >> 6;
    unsigned long long run = 0ull;
    for (int c = w; c < nch; c += 4) {
        int j = (c << 6) + l;
        unsigned long long xx = (j < ne) ? cand[j] : 0ull;
        xx = awm_sort64_u64(xx, l);
        unsigned long long rv = __shfl(xx, 63 - l);
        run = (run > rv) ? run : rv;
        run = awm_merge64_u64(run, l);
    }
    if (l < 32) wtop[w * 32 + l] = run;
    __syncthreads();
    if (w == 0) {
        unsigned long long a = (l < 32) ? wtop[l] : wtop[32 + (63 - l)];
        a = awm_merge64_u64(a, l);
        unsigned long long b = (l < 32) ? wtop[64 + l] : wtop[96 + (63 - l)];
        b = awm_merge64_u64(b, l);
        unsigned long long z = (l < 32) ? a : __shfl(b, 63 - l);
        z = awm_merge64_u64(z, l);
        if (l < 32)
            topidx[r * TOPK_ + l] =
                (int)(0xFFFFFFFFu - (unsigned)(z & 0xFFFFFFFFull));
    }
}

// ---------------- histogram radix-select (chunked fallback) ----------------
__global__ __launch_bounds__(256) void awm_seltop_kernel(
    const float* __restrict__ selc, int ld, int chunk_arg,
    float* __restrict__ cand_val, int* __restrict__ cand_idx) {
    int r = blockIdx.x;
    int chunk = (chunk_arg >= 0) ? chunk_arg : (int)blockIdx.y;
    int col0 = (ld == NMEM_) ? chunk * SELC_ : 0;
    int tid = threadIdx.x;
    __shared__ unsigned hist[4096];
    __shared__ float eqv[EQCAP_];
    __shared__ unsigned eqi[EQCAP_];
    __shared__ float abv_v[32];
    __shared__ unsigned abv_i[32];
    __shared__ int ctrs[2];
    __shared__ int binfo[1];
    for (int i = tid; i < 4096; i += 256) hist[i] = 0u;
    if (tid < 2) ctrs[tid] = 0;
    if (tid == 0) binfo[0] = 0;
    __syncthreads();
    const float* src = selc + (size_t)r * ld + col0;
    float4 vv[8];
#pragma unroll
    for (int p = 0; p < 8; ++p)
        vv[p] = *(const float4*)&src[(tid << 2) + (p << 10)];
#pragma unroll
    for (int p = 0; p < 8; ++p) {
        atomicAdd(&hist[awm_ordkey(vv[p].x) >> 20], 1u);
        atomicAdd(&hist[awm_ordkey(vv[p].y) >> 20], 1u);
        atomicAdd(&hist[awm_ordkey(vv[p].z) >> 20], 1u);
        atomicAdd(&hist[awm_ordkey(vv[p].w) >> 20], 1u);
    }
    __syncthreads();
    if (tid < 64) {
        int lane = tid;
        unsigned s = 0;
        for (int j = 0; j < 64; ++j)
            s += hist[(lane << 6) + ((j + lane) & 63)];
        unsigned suf = s;
#pragma unroll
        for (int off = 1; off < 64; off <<= 1) {
            unsigned t2 = __shfl_down(suf, off);
            suf += (lane + off < 64) ? t2 : 0u;
        }
        unsigned nd = __shfl_down(suf, 1);
        unsigned nxt = (lane == 63) ? 0u : nd;
        bool cross = (suf >= (unsigned)TOPK_) && (nxt < (unsigned)TOPK_);
        unsigned long long mc = __ballot(cross ? 1 : 0);
        int sstar = (mc == 0ull) ? 63 : (int)__builtin_ctzll(mc);
        unsigned above_super = (mc == 0ull) ? 0u : __shfl(nxt, sstar);
        unsigned suf2 = hist[(sstar << 6) + lane];
#pragma unroll
        for (int off = 1; off < 64; off <<= 1) {
            unsigned t2 = __shfl_down(suf2, off);
            suf2 += (lane + off < 64) ? t2 : 0u;
        }
        unsigned tot = suf2 + above_super;
        unsigned nd2 = __shfl_down(tot, 1);
        unsigned nxt2 = (lane == 63) ? above_super : nd2;
        bool cross2 = (tot >= (unsigned)TOPK_) && (nxt2 < (unsigned)TOPK_);
        if (cross2) binfo[0] = (sstar << 6) + lane;
    }
    __syncthreads();
    int theta = binfo[0];
    int gbase = chunk * SELC_;
#pragma unroll
    for (int p = 0; p < 8; ++p) {
        float fv[4] = {vv[p].x, vv[p].y, vv[p].z, vv[p].w};
#pragma unroll
        for (int c = 0; c < 4; ++c) {
            int bin = (int)(awm_ordkey(fv[c]) >> 20);
            if (bin >= theta) {
                unsigned li = (unsigned)((tid << 2) + (p << 10) + c);
                if (bin > theta) {
                    int pos = atomicAdd(&ctrs[0], 1);
                    if (pos < 32) { abv_v[pos] = fv[c]; abv_i[pos] = li; }
                } else {
                    int pos = atomicAdd(&ctrs[1], 1);
                    if (pos < EQCAP_) { eqv[pos] = fv[c]; eqi[pos] = li; }
                }
            }
        }
    }
    __syncthreads();
    if (tid < 64) {
        int lane = tid;
        int na = ctrs[0]; if (na > TOPK_) na = TOPK_;
        int ne = ctrs[1]; if (ne > EQCAP_) ne = EQCAP_;
        float* cvp = cand_val + (size_t)r * 128 + chunk * 32;
        int* cip = cand_idx + (size_t)r * 128 + chunk * 32;
        if (lane < na) { cvp[lane] = abv_v[lane]; cip[lane] = gbase + (int)abv_i[lane]; }
        int need = TOPK_ - na;
        unsigned deadm = 0u;
        for (int it = 0; it < need; ++it) {
            float bv = -INFINITY; unsigned bi = 0xFFFFFFFFu; int bs = -1;
            int jj = 0;
            for (int j = lane; j < ne; j += 64, ++jj) {
                if (!((deadm >> jj) & 1u)) {
                    float vq = eqv[j]; unsigned iq = eqi[j];
                    if (vq > bv || (vq == bv && iq < bi)) { bv = vq; bi = iq; bs = j; }
                }
            }
#pragma unroll
            for (int off = 32; off > 0; off >>= 1) {
                float ov = __shfl_xor(bv, off);
                unsigned oi = __shfl_xor(bi, off);
                int os = __shfl_xor(bs, off);
                if (ov > bv || (ov == bv && oi < bi)) { bv = ov; bi = oi; bs = os; }
            }
            if (lane == 0) {
                int gi = (bi == 0xFFFFFFFFu) ? gbase : (gbase + (int)bi);
                cvp[na + it] = bv; cip[na + it] = gi;
            }
            if (bs >= 0 && (bs & 63) == lane) deadm |= (1u << (bs >> 6));
        }
    }
}

// ---------------- merge 4x32 candidates -> global top-32 (fallback only) ----------------
__global__ __launch_bounds__(64) void awm_merge_kernel(
    const float* __restrict__ cand_val, const int* __restrict__ cand_idx,
    int* __restrict__ topidx) {
    int r = blockIdx.x;
    int lane = threadIdx.x;
    float v0 = cand_val[(size_t)r * 128 + lane];
    float v1 = cand_val[(size_t)r * 128 + 64 + lane];
    int i0 = cand_idx[(size_t)r * 128 + lane];
    int i1 = cand_idx[(size_t)r * 128 + 64 + lane];
    for (int it = 0; it < TOPK_; ++it) {
        float v; int ix;
        if (v0 > v1 || (v0 == v1 && i0 < i1)) { v = v0; ix = i0; } else { v = v1; ix = i1; }
#pragma unroll
        for (int off = 32; off > 0; off >>= 1) {
            float ov = __shfl_xor(v, off);
            int oi = __shfl_xor(ix, off);
            if (ov > v || (ov == v && oi < ix)) { v = ov; ix = oi; }
        }
        if (lane == 0) topidx[r * TOPK_ + it] = ix;
        if (ix == i0) v0 = -INFINITY;
        else if (ix == i1) v1 = -INFINITY;
    }
}

// ---------------- hidden proj GEMM: hq = q@W1q + bs1 (y=0), hkc = k@W1k (y=1) ----------------
__global__ __launch_bounds__(256) void awm_hid_kernel(
    const float* __restrict__ q_flat, const float* __restrict__ k_flat,
    const float* __restrict__ Ws1, const float* __restrict__ bs1,
    float* __restrict__ hq, float* __restrict__ hkc) {
    int isK = blockIdx.y;
    int bm = blockIdx.x * 32;
    int tid = threadIdx.x;
    __shared__ float As[64][34];
    __shared__ float Ws_s[64][132];
    const float* src = isK ? k_flat : q_flat;
    const float* W = Ws1 + (isK ? (size_t)DH_ * HID_ : 0);
    {
        int m = tid >> 3, kq = (tid & 7) * 8;
        int rho = bm + m;
        int bh = rho >> 8, t = rho & 255;
        int b = bh >> 3, h = bh & 7;
        const float* sp = src + (size_t)(b * T_ + t) * HD_ + h * DH_ + kq;
        float4 a = *(const float4*)sp;
        float4 c = *(const float4*)(sp + 4);
        As[kq+0][m] = a.x; As[kq+1][m] = a.y; As[kq+2][m] = a.z; As[kq+3][m] = a.w;
        As[kq+4][m] = c.x; As[kq+5][m] = c.y; As[kq+6][m] = c.z; As[kq+7][m] = c.w;
    }
    for (int i = tid; i < 64 * HID_ / 4; i += 256) {
        int k = (i * 4) >> 7, f = (i * 4) & 127;
        *(float4*)&Ws_s[k][f] = *(const float4*)&W[(size_t)k * HID_ + f];
    }
    __syncthreads();
    int tm = (tid >> 4) * 2, tn = (tid & 15) * 8;
    float acc[2][8] = {};
#pragma unroll 8
    for (int k = 0; k < DH_; ++k) {
        float2 a2 = *(const float2*)&As[k][tm];
        float4 b0 = *(const float4*)&Ws_s[k][tn];
        float4 b1 = *(const float4*)&Ws_s[k][tn + 4];
        float av[2] = {a2.x, a2.y};
        float bv[8] = {b0.x, b0.y, b0.z, b0.w, b1.x, b1.y, b1.z, b1.w};
#pragma unroll
        for (int x = 0; x < 2; ++x)
#pragma unroll
            for (int y = 0; y < 8; ++y) acc[x][y] += av[x] * bv[y];
    }
    float* out = isK ? hkc : hq;
#pragma unroll
    for (int x = 0; x < 2; ++x) {
        int rho = bm + tm + x;
        float vv[8];
#pragma unroll
        for (int y = 0; y < 8; ++y)
            vv[y] = acc[x][y] + (isK ? 0.f : bs1[tn + y]);
        float4 r0, r1;
        r0.x = vv[0]; r0.y = vv[1]; r0.z = vv[2]; r0.w = vv[3];
        r1.x = vv[4]; r1.y = vv[5]; r1.z = vv[6]; r1.w = vv[7];
        float* op = out + (size_t)rho * HID_ + tn;
        *(float4*)op = r0; *(float4*)(op + 4) = r1;
    }
}

// ---------------- fused: hk_mem + mem scores, one block per (b,t) ----------------
__global__ __launch_bounds__(256) void awm_smem_kernel(
    const float* __restrict__ hq, const float* __restrict__ mkeys,
    const int* __restrict__ topidx, const float* __restrict__ Ws1,
    const float* __restrict__ Ws2, float* __restrict__ smem_out) {
    int bt = blockIdx.x;
    int b = bt >> 8, t = bt & 255;
    int tid = threadIdx.x;
    __shared__ float W1k_s[32][132];
    __shared__ float mk_s[64][36];
    __shared__ float hkm_s[32][133];
    __shared__ float hq_s[8][132];
    __shared__ float w2_s[HID_];
    __shared__ int key_s[TOPK_];
    {
        int h = tid >> 5, fq = (tid & 31) * 4;
        *(float4*)&hq_s[h][fq] =
            *(const float4*)&hq[((size_t)(b * H_ + h) * T_ + t) * HID_ + fq];
    }
    if (tid < HID_) w2_s[tid] = Ws2[tid];
    if (tid < TOPK_) key_s[tid] = topidx[bt * TOPK_ + tid];
    __syncthreads();
    {
        int j = tid >> 3, kq = (tid & 7) * 8;
        const float* sp = mkeys + (size_t)key_s[j] * DH_ + kq;
        float4 a = *(const float4*)sp;
        float4 c = *(const float4*)(sp + 4);
        mk_s[kq+0][j] = a.x; mk_s[kq+1][j] = a.y; mk_s[kq+2][j] = a.z; mk_s[kq+3][j] = a.w;
        mk_s[kq+4][j] = c.x; mk_s[kq+5][j] = c.y; mk_s[kq+6][j] = c.z; mk_s[kq+7][j] = c.w;
    }
    int j0 = (tid >> 5) * 4, f0 = (tid & 31) * 4;
    float acc[4][4] = {};
    for (int kc = 0; kc < 2; ++kc) {
        __syncthreads();
        for (int i = tid; i < 32 * HID_ / 4; i += 256) {
            int k = (i * 4) >> 7, f = (i * 4) & 127;
            *(float4*)&W1k_s[k][f] =
                *(const float4*)&Ws1[(size_t)(DH_ + kc * 32 + k) * HID_ + f];
        }
        __syncthreads();
#pragma unroll 8
        for (int k = 0; k < 32; ++k) {
            float4 a4 = *(const float4*)&mk_s[kc * 32 + k][j0];
            float4 b4 = *(const float4*)&W1k_s[k][f0];
            float av[4] = {a4.x, a4.y, a4.z, a4.w};
            float bv[4] = {b4.x, b4.y, b4.z, b4.w};
#pragma unroll
            for (int x = 0; x < 4; ++x)
#pragma unroll
                for (int y = 0; y < 4; ++y) acc[x][y] += av[x] * bv[y];
        }
    }
#pragma unroll
    for (int x = 0; x < 4; ++x)
#pragma unroll
        for (int y = 0; y < 4; ++y) hkm_s[j0 + x][f0 + y] = acc[x][y];
    __syncthreads();
    int h = tid >> 5, j = tid & 31;
    float sacc = 0.f;
#pragma unroll 8
    for (int f = 0; f < HID_; ++f) {
        float u = hq_s[h][f] + hkm_s[j][f];
        sacc += fmaxf(u, 0.f) * w2_s[f];
    }
    smem_out[((size_t)(b * H_ + h) * T_ + t) * TOPK_ + j] = sacc;
}

// ---------------- fused ctx scores + softmax + PV + gate; block = (b,h, 16-t tile), 512 thr ----------------
__global__ __launch_bounds__(512) void awm_attn2_kernel(
    const float* __restrict__ hq, const float* __restrict__ hkc,
    const float* __restrict__ smem_in, const float* __restrict__ v_flat,
    const float* __restrict__ mem_values, const int* __restrict__ topidx,
    const float* __restrict__ Ws2, const float* __restrict__ gates,
    float* __restrict__ outg) {
    int tb = blockIdx.x;       // 0..15
    int bh = blockIdx.y;
    int b = bh >> 3, h = bh & 7;
    int tbase = tb * TT_;
    int tid = threadIdx.x;     // 0..511
    __shared__ float hq_s[HID_][TT_ + 2];   // [128][18]
    __shared__ float hk_s[32][260];
    __shared__ float sc[TT_][292];
    __shared__ float w2_s[HID_];
    __shared__ int idx_s[TT_][TOPK_];
    {
        int t = tid >> 5, fq = (tid & 31) * 4;
        float4 a = *(const float4*)&hq[((size_t)bh * T_ + tbase + t) * HID_ + fq];
        hq_s[fq+0][t] = a.x; hq_s[fq+1][t] = a.y; hq_s[fq+2][t] = a.z; hq_s[fq+3][t] = a.w;
    }
    if (tid < HID_) w2_s[tid] = Ws2[tid];
    {
        int t = tid >> 5, j = tid & 31;
        sc[t][256 + j] = smem_in[((size_t)bh * T_ + tbase + t) * TOPK_ + j];
        idx_s[t][j] = topidx[((size_t)b * T_ + tbase + t) * TOPK_ + j];
    }
    int t0 = (tid >> 6) * 2, s0 = (tid & 63) * 4;
    float acc[2][4] = {};
    for (int fc = 0; fc < 4; ++fc) {
        __syncthreads();
        {   // stage hk_s[32f][256s]: 4 float4/thread
            int f4 = (tid & 7) * 4, sr = tid >> 3;   // sr 0..63
#pragma unroll
            for (int p = 0; p < 4; ++p) {
                int s = sr + p * 64;
                float4 a = *(const float4*)&hkc[((size_t)bh * T_ + s) * HID_ + fc * 32 + f4];
                hk_s[f4+0][s] = a.x; hk_s[f4+1][s] = a.y; hk_s[f4+2][s] = a.z; hk_s[f4+3][s] = a.w;
            }
        }
        __syncthreads();
#pragma unroll 8
        for (int f = 0; f < 32; ++f) {
            float2 a2 = *(const float2*)&hq_s[fc * 32 + f][t0];
            float4 b4 = *(const float4*)&hk_s[f][s0];
            float w2f = w2_s[fc * 32 + f];
            float av[2] = {a2.x, a2.y};
            float bv[4] = {b4.x, b4.y, b4.z, b4.w};
#pragma unroll
            for (int x = 0; x < 2; ++x)
#pragma unroll
                for (int y = 0; y < 4; ++y)
                    acc[x][y] += fmaxf(av[x] + bv[y], 0.f) * w2f;
        }
    }
    {
        float4 r0, r1;
        r0.x = acc[0][0]; r0.y = acc[0][1]; r0.z = acc[0][2]; r0.w = acc[0][3];
        r1.x = acc[1][0]; r1.y = acc[1][1]; r1.z = acc[1][2]; r1.w = acc[1][3];
        *(float4*)&sc[t0][s0] = r0;
        *(float4*)&sc[t0 + 1][s0] = r1;
    }
    __syncthreads();
    {
        int t = tid >> 5, l = tid & 31;
        float mx = -INFINITY;
#pragma unroll
        for (int k = 0; k < 9; ++k) mx = fmaxf(mx, sc[t][l + 32 * k]);
#pragma unroll
        for (int off = 16; off > 0; off >>= 1) mx = fmaxf(mx, __shfl_xor(mx, off, 32));
        float sum = 0.f;
#pragma unroll
        for (int k = 0; k < 9; ++k) {
            float e = expf(sc[t][l + 32 * k] - mx);
            sc[t][l + 32 * k] = e;
            sum += e;
        }
#pragma unroll
        for (int off = 16; off > 0; off >>= 1) sum += __shfl_xor(sum, off, 32);
        float inv = 1.f / sum;
#pragma unroll
        for (int k = 0; k < 9; ++k) sc[t][l + 32 * k] *= inv;
    }
    __syncthreads();
    {
        int g = tid >> 6, l = tid & 63;   // g 0..7
        int ta = 2 * g, tbb = 2 * g + 1;
        const float* vb = v_flat + (size_t)b * T_ * HD_ + h * DH_ + l;
        float a0 = 0.f, a1 = 0.f;
#pragma unroll 8
        for (int s = 0; s < T_; ++s) {
            float vv = vb[(size_t)s * HD_];
            a0 += sc[ta][s] * vv;
            a1 += sc[tbb][s] * vv;
        }
#pragma unroll 4
        for (int j = 0; j < TOPK_; ++j) {
            a0 += sc[ta][256 + j] * mem_values[(size_t)idx_s[ta][j] * DH_ + l];
            a1 += sc[tbb][256 + j] * mem_values[(size_t)idx_s[tbb][j] * DH_ + l];
        }
        float g0 = gates[(size_t)(b * T_ + tbase + ta) * H_ + h];
        float g1v = gates[(size_t)(b * T_ + tbase + tbb) * H_ + h];
        outg[(size_t)(b * T_ + tbase + ta) * HD_ + h * DH_ + l] = a0 * g0;
        outg[(size_t)(b * T_ + tbase + tbb) * HD_ + h * DH_ + l] = a1 * g1v;
    }
}

extern "C" void kernel_launch(void* const* d_in, const int* in_sizes, int n_in,
                              void* d_out, int out_size, void* d_ws, size_t ws_size,
                              hipStream_t stream) {
    (void)in_sizes; (void)n_in; (void)out_size;
    const float* x    = (const float*)d_in[0];
    const float* Wq   = (const float*)d_in[1];
    const float* Wk   = (const float*)d_in[2];
    const float* Wv   = (const float*)d_in[3];
    const float* Wo   = (const float*)d_in[4];
    const float* Wg1  = (const float*)d_in[5];
    const float* bg1  = (const float*)d_in[6];
    const float* Wg2  = (const float*)d_in[7];
    const float* bg2  = (const float*)d_in[8];
    const float* Ws1  = (const float*)d_in[9];
    const float* bs1  = (const float*)d_in[10];
    const float* Ws2  = (const float*)d_in[11];
    const float* mk   = (const float*)d_in[13];
    const float* mv   = (const float*)d_in[14];
    float* y = (float*)d_out;

    float* w = (float*)d_ws;
    size_t off = 0;
    float* q_flat = w + off; off += (size_t)BT_ * HD_;
    float* k_flat = w + off; off += (size_t)BT_ * HD_;
    float* v_flat = w + off; off += (size_t)BT_ * HD_;
    float* gates  = w + off; off += (size_t)BT_ * H_;
    float* qm     = w + off; off += (size_t)BT_ * DH_;
    float* hq     = w + off; off += (size_t)B_ * H_ * T_ * HID_;
    float* hkc    = w + off; off += (size_t)B_ * H_ * T_ * HID_;
    float* smemb  = w + off; off += (size_t)B_ * H_ * T_ * TOPK_;
    float* outg   = w + off; off += (size_t)BT_ * HD_;
    float* cand_v = w + off; off += (size_t)BT_ * 128;
    int*   cand_i = (int*)(w + off); off += (size_t)BT_ * 128;
    int*   topidx = (int*)(w + off); off += (size_t)BT_ * TOPK_;
    float* tmax   = w + off; off += (size_t)BT_ * NTILE_;
    float* selc   = w + off;
    int fullw = (ws_size >= (off + (size_t)BT_ * NMEM_) * sizeof(float));

    dim3 thr256(256);
    awm_qkvg_kernel<<<dim3(8, 16, 4), thr256, 0, stream>>>(
        x, Wq, Wk, Wv, Wg1, bg1, Wg2, bg2, q_flat, k_flat, v_flat, gates);
    awm_qmean_kernel<<<dim3((BT_ * DH_ + 255) / 256), thr256, 0, stream>>>(q_flat, qm);
    if (fullw) {
        awm_selgemm_kernel<<<dim3(NMEM_ / 128, BT_ / 64), thr256, 0, stream>>>(
            qm, mk, selc, tmax, 0, NMEM_);
        awm_selfilter_kernel<<<dim3(BT_), thr256, 0, stream>>>(selc, tmax, topidx);
    } else {
        for (int c = 0; c < NCHUNK_; ++c) {
            awm_selgemm_kernel<<<dim3(SELC_ / 128, BT_ / 64), thr256, 0, stream>>>(
                qm, mk, selc, tmax, c * SELC_, SELC_);
            awm_seltop_kernel<<<dim3(BT_, 1), thr256, 0, stream>>>(
                selc, SELC_, c, cand_v, cand_i);
        }
        awm_merge_kernel<<<dim3(BT_), dim3(64), 0, stream>>>(cand_v, cand_i, topidx);
    }
    awm_hid_kernel<<<dim3(B_ * H_ * T_ / 32, 2), thr256, 0, stream>>>(
        q_flat, k_flat, Ws1, bs1, hq, hkc);
    awm_smem_kernel<<<dim3(BT_), thr256, 0, stream>>>(hq, mk, topidx, Ws1, Ws2, smemb);
    awm_attn2_kernel<<<dim3(T_ / TT_, B_ * H_), dim3(512), 0, stream>>>(
        hq, hkc, smemb, v_flat, mv, topidx, Ws2, gates, outg);
    awm_out_kernel<<<dim3(8, 16), thr256, 0, stream>>>(outg, Wo, y);
}